// Round 12
// baseline (288.285 us; speedup 1.0000x reference)
//
#include <hip/hip_runtime.h>
#include <hip/hip_bf16.h>

// N=50000 nodes, E=800000 edges, D=96 (in = hidden = out)
#define NNODES 50000
#define NEDGES 800000
#define DIM    96
#define HC     48       // half-columns per aggregation pass (4.8MB buffer fits XCD L2)
#define NBUCK  196      // ceil(N/256): bucket = dst >> 8
#define PCHUNK 3125     // edges per partition block (256 * 3125 = 800000)
#define TM     64       // rows per GEMM block
#define XPAD   104      // LDS row stride (bf16), 16B-aligned

typedef __attribute__((ext_vector_type(8))) short   short8;   // 8 bf16 = 4 VGPRs
typedef __attribute__((ext_vector_type(4))) float   float4v;  // MFMA acc

// flags[0] = 1 if float tensors are bf16, 0 if f32
// flags[1] = 1 if edge_index is int64, 0 if int32
__device__ __forceinline__ float loadF(const void* p, long i, int isbf) {
    return isbf ? __bfloat162float(((const __hip_bfloat16*)p)[i])
                : ((const float*)p)[i];
}
__device__ __forceinline__ int clampN(int v) {
    return v < 0 ? 0 : (v >= NNODES ? NNODES - 1 : v);
}
__device__ __forceinline__ int edgeDst(const int* w, int e, int is64) {
    return clampN(is64 ? w[2 * (NEDGES + e)] : w[NEDGES + e]);
}
__device__ __forceinline__ int edgeSrc(const int* w, int e, int is64) {
    return clampN(is64 ? w[2 * e] : w[e]);
}

// single wave: sniff dtypes; also zero bcnt (replaces a memset dispatch)
__global__ void k_sniff(const unsigned* __restrict__ xw,
                        const unsigned* __restrict__ ew,
                        int* __restrict__ flags,
                        int* __restrict__ bcnt) {
    int lane = threadIdx.x;
    for (int i = lane; i < NBUCK; i += 64) bcnt[i] = 0;
    int bad = 0, nz = 0;
    for (int r = 0; r < 4; ++r) {
        unsigned w  = xw[lane + 64 * r];
        unsigned lo = w & 0xffffu;
        unsigned ex = (lo >> 7) & 0xffu;
        if (!(lo == 0u || (ex >= 90u && ex <= 145u))) bad++;
        unsigned o = ew[2 * (lane + 64 * r) + 1];
        if (o != 0u) nz++;
    }
    for (int off = 32; off; off >>= 1) {
        bad += __shfl_down(bad, off);
        nz  += __shfl_down(nz,  off);
    }
    if (lane == 0) {
        flags[0] = (bad <= 32) ? 1 : 0;
        flags[1] = (nz  <  4) ? 1 : 0;
    }
}

// bucket counts: per-block LDS histogram, then 196 global adds per block
__global__ __launch_bounds__(256) void k_bcount(const int* __restrict__ w,
                                                int* __restrict__ bcnt,
                                                const int* __restrict__ flags) {
    __shared__ int h[NBUCK];
    const int is64 = flags[1];
    for (int i = threadIdx.x; i < NBUCK; i += 256) h[i] = 0;
    __syncthreads();
    const int nth = gridDim.x * blockDim.x;
    for (int e = blockIdx.x * blockDim.x + threadIdx.x; e < NEDGES; e += nth)
        atomicAdd(&h[edgeDst(w, e, is64) >> 8], 1);
    __syncthreads();
    for (int i = threadIdx.x; i < NBUCK; i += 256)
        if (h[i]) atomicAdd(&bcnt[i], h[i]);
}

// exclusive scan of 196 bucket counts -> bbase, bcur; seal rowptr[N]
__global__ __launch_bounds__(256) void k_bscan(const int* __restrict__ bcnt,
                                               int* __restrict__ bbase,
                                               int* __restrict__ bcur,
                                               int* __restrict__ rowptr) {
    __shared__ int s[256];
    const int tid = threadIdx.x;
    int v = (tid < NBUCK) ? bcnt[tid] : 0;
    s[tid] = v;
    __syncthreads();
    for (int off = 1; off < 256; off <<= 1) {
        int t = (tid >= off) ? s[tid - off] : 0;
        __syncthreads();
        s[tid] += t;
        __syncthreads();
    }
    int excl = s[tid] - v;
    if (tid < NBUCK) { bbase[tid] = excl; bcur[tid] = excl; }
    if (tid == 0) { bbase[NBUCK] = NEDGES; rowptr[NNODES] = NEDGES; }
}

// partition edges into bucket regions as packed (dst<<16)|src u32 records.
__global__ __launch_bounds__(256) void k_part(const int* __restrict__ w,
                                              int* __restrict__ bcur,
                                              unsigned* __restrict__ ebuf,
                                              const int* __restrict__ flags) {
    __shared__ int h[NBUCK];
    __shared__ int base[NBUCK];
    const int is64 = flags[1];
    const int e0 = blockIdx.x * PCHUNK;
    const int e1 = (e0 + PCHUNK < NEDGES) ? e0 + PCHUNK : NEDGES;

    for (int i = threadIdx.x; i < NBUCK; i += 256) h[i] = 0;
    __syncthreads();
    for (int e = e0 + threadIdx.x; e < e1; e += 256)
        atomicAdd(&h[edgeDst(w, e, is64) >> 8], 1);
    __syncthreads();
    for (int i = threadIdx.x; i < NBUCK; i += 256) {
        int c = h[i];
        base[i] = c ? atomicAdd(&bcur[i], c) : 0;
        h[i] = 0;                        // reuse as local cursor
    }
    __syncthreads();
    for (int e = e0 + threadIdx.x; e < e1; e += 256) {
        int s = edgeSrc(w, e, is64);
        int d = edgeDst(w, e, is64);
        int b = d >> 8;
        int pos = base[b] + atomicAdd(&h[b], 1);
        ebuf[pos] = ((unsigned)d << 16) | (unsigned)s;
    }
}

// per-bucket local CSR: histogram 256 local dsts, scan -> rowptr/dinv,
// LDS-cursor scatter of col (uint16). All writes block/XCD-local.
__global__ __launch_bounds__(256) void k_csr(const unsigned* __restrict__ ebuf,
                                             const int* __restrict__ bbase,
                                             int* __restrict__ rowptr,
                                             unsigned short* __restrict__ col,
                                             float* __restrict__ dinv) {
    __shared__ int h[256];
    __shared__ int sc[256];
    __shared__ int cur[256];
    const int b   = blockIdx.x;
    const int tid = threadIdx.x;
    const int e0 = bbase[b], e1 = bbase[b + 1];

    h[tid] = 0;
    __syncthreads();
    for (int e = e0 + tid; e < e1; e += 256)
        atomicAdd(&h[(ebuf[e] >> 16) & 255], 1);
    __syncthreads();
    int v = h[tid];
    sc[tid] = v;
    __syncthreads();
    for (int off = 1; off < 256; off <<= 1) {
        int t = (tid >= off) ? sc[tid - off] : 0;
        __syncthreads();
        sc[tid] += t;
        __syncthreads();
    }
    int start = e0 + sc[tid] - v;       // exclusive
    cur[tid] = start;
    int node = b * 256 + tid;
    if (node < NNODES) {
        rowptr[node] = start;
        dinv[node] = rsqrtf((float)v + 1.0f);   // +1 self loop
    }
    __syncthreads();
    for (int e = e0 + tid; e < e1; e += 256) {
        unsigned r = ebuf[e];
        int dl = (r >> 16) & 255;
        int pos = atomicAdd(&cur[dl], 1);
        col[pos] = (unsigned short)(r & 0xffffu);
    }
}

// MFMA GEMM with column-split bf16 output (and optionally split input):
// gA[row][0..47], gB[row][48..95] = bf16( dinv[row] * (X[row,:] @ W) )
__global__ __launch_bounds__(256) void k_gemm_mfma(
        const void* __restrict__ Xd,              // dense input (layer 1) or null
        const __hip_bfloat16* __restrict__ XA,    // split input (layer 2)
        const __hip_bfloat16* __restrict__ XB,
        const void* __restrict__ W,
        const float* __restrict__ dinv,
        __hip_bfloat16* __restrict__ gA,
        __hip_bfloat16* __restrict__ gB,
        const int* __restrict__ flags) {
    __shared__ __hip_bfloat16 Xs[TM * XPAD];
    __shared__ __hip_bfloat16 Wt[DIM * XPAD];

    const int t    = threadIdx.x;
    const int fbf  = flags[0];
    const int row0 = blockIdx.x * TM;

    for (int idx = t; idx < DIM * DIM; idx += 256) {
        int k = idx / DIM, n = idx - k * DIM;
        Wt[n * XPAD + k] = __float2bfloat16(loadF(W, idx, fbf));
    }
    for (int idx = t; idx < TM * DIM; idx += 256) {
        int r = idx / DIM, c = idx - r * DIM;
        int gr = row0 + r;
        float v = 0.f;
        if (gr < NNODES) {
            if (Xd) v = loadF(Xd, (long)gr * DIM + c, fbf);
            else    v = __bfloat162float(c < HC ? XA[(size_t)gr * HC + c]
                                                : XB[(size_t)gr * HC + c - HC]);
        }
        Xs[r * XPAD + c] = __float2bfloat16(v);
    }
    __syncthreads();

    const int wave = t >> 6;
    const int lane = t & 63;
    const int m    = lane & 15;
    const int quad = lane >> 4;

    const short* xsp = (const short*)Xs;
    short8 a[3];
#pragma unroll
    for (int kt = 0; kt < 3; ++kt)
        a[kt] = *(const short8*)(xsp + (wave * 16 + m) * XPAD + kt * 32 + quad * 8);

    float dv[4];
#pragma unroll
    for (int r2 = 0; r2 < 4; ++r2) {
        int gr = row0 + wave * 16 + quad * 4 + r2;
        dv[r2] = (gr < NNODES) ? dinv[gr] : 0.f;
    }

    const short* wtp = (const short*)Wt;
#pragma unroll
    for (int nt = 0; nt < 6; ++nt) {
        float4v acc = {0.f, 0.f, 0.f, 0.f};
#pragma unroll
        for (int kt = 0; kt < 3; ++kt) {
            short8 b = *(const short8*)(wtp + (nt * 16 + m) * XPAD + kt * 32 + quad * 8);
            acc = __builtin_amdgcn_mfma_f32_16x16x32_bf16(a[kt], b, acc, 0, 0, 0);
        }
        int cidx = nt * 16 + m;                      // global column
        __hip_bfloat16* dst = (cidx < HC) ? gA : gB;
        int cc = (cidx < HC) ? cidx : cidx - HC;
#pragma unroll
        for (int r2 = 0; r2 < 4; ++r2) {
            int gr = row0 + wave * 16 + quad * 4 + r2;
            if (gr < NNODES)
                dst[(size_t)gr * HC + cc] = __float2bfloat16(acc[r2] * dv[r2]);
        }
    }
}

// half-column aggregate: ONE WAVE per dst row over one 48-col half (4.8MB,
// XCD-L2 resident). Lanes 0..23 gather edge i's 96B half-row, lanes 32..55
// edge i+1's; one shfl_xor(32) combine. Epilogue: dinv*acc + b [,PReLU].
// out: elem index row*ostride + ocol0 + 2l (bf16 unless fbf==0 && !prelu).
__global__ __launch_bounds__(256) void k_aggr(
        const __hip_bfloat16* __restrict__ gh,    // half buffer, N x 48
        const int* __restrict__ rowptr,
        const unsigned short* __restrict__ col,
        const float* __restrict__ dinv,
        const void* __restrict__ b,
        const void* __restrict__ a1,
        void* __restrict__ out,
        const int* __restrict__ flags,
        int prelu, int bcol0, int ostride, int ocol0) {
    const int wave = threadIdx.x >> 6;
    const int lane = threadIdx.x & 63;
    const int row  = blockIdx.x * 4 + wave;
    if (row >= NNODES) return;                       // wave-uniform (N%4==0)
    const int fbf = flags[0];
    const int sub = lane >> 5;                       // 0/1: which edge of pair
    const int l   = lane & 31;                       // 0..23 active
    const __hip_bfloat162* gv = (const __hip_bfloat162*)gh;

    float2 acc = {0.f, 0.f};
    if (sub == 0 && l < 24)                          // self loop once
        acc = __bfloat1622float2(gv[(size_t)row * 24 + l]);

    const int p0 = rowptr[row], p1 = rowptr[row + 1];
    int i = p0;
    for (; i + 16 <= p1; i += 16) {                  // 8 pairs in flight
        int s[8];
#pragma unroll
        for (int k = 0; k < 8; ++k) s[k] = col[i + 2 * k + sub];
        if (l < 24) {
            float2 v[8];
#pragma unroll
            for (int k = 0; k < 8; ++k)
                v[k] = __bfloat1622float2(gv[(size_t)s[k] * 24 + l]);
            acc.x += ((v[0].x + v[1].x) + (v[2].x + v[3].x))
                   + ((v[4].x + v[5].x) + (v[6].x + v[7].x));
            acc.y += ((v[0].y + v[1].y) + (v[2].y + v[3].y))
                   + ((v[4].y + v[5].y) + (v[6].y + v[7].y));
        }
    }
    for (; i + 8 <= p1; i += 8) {                    // 4 pairs
        int s[4];
#pragma unroll
        for (int k = 0; k < 4; ++k) s[k] = col[i + 2 * k + sub];
        if (l < 24) {
            float2 v[4];
#pragma unroll
            for (int k = 0; k < 4; ++k)
                v[k] = __bfloat1622float2(gv[(size_t)s[k] * 24 + l]);
            acc.x += (v[0].x + v[1].x) + (v[2].x + v[3].x);
            acc.y += (v[0].y + v[1].y) + (v[2].y + v[3].y);
        }
    }
    for (; i + 2 <= p1; i += 2) {                    // 1 pair
        int s0 = col[i + sub];
        if (l < 24) {
            float2 v = __bfloat1622float2(gv[(size_t)s0 * 24 + l]);
            acc.x += v.x; acc.y += v.y;
        }
    }
    if (i < p1 && sub == 0) {                        // odd tail
        int s0 = col[i];
        if (l < 24) {
            float2 v = __bfloat1622float2(gv[(size_t)s0 * 24 + l]);
            acc.x += v.x; acc.y += v.y;
        }
    }

    acc.x += __shfl_xor(acc.x, 32);                  // combine pair halves
    acc.y += __shfl_xor(acc.y, 32);

    if (sub == 0 && l < 24) {
        float dv = dinv[row];
        float vx = dv * acc.x + loadF(b, bcol0 + 2 * l,     fbf);
        float vy = dv * acc.y + loadF(b, bcol0 + 2 * l + 1, fbf);
        if (prelu) {
            float alpha = loadF(a1, 0, fbf);
            vx = vx > 0.f ? vx : alpha * vx;
            vy = vy > 0.f ? vy : alpha * vy;
        }
        size_t base2 = ((size_t)row * ostride + ocol0) / 2 + l;
        if (prelu || fbf) {
            ((__hip_bfloat162*)out)[base2] =
                __halves2bfloat162(__float2bfloat16(vx), __float2bfloat16(vy));
        } else {
            float2 o; o.x = vx; o.y = vy;
            ((float2*)out)[base2] = o;
        }
    }
}

extern "C" void kernel_launch(void* const* d_in, const int* in_sizes, int n_in,
                              void* d_out, int out_size, void* d_ws, size_t ws_size,
                              hipStream_t stream) {
    const void* x  = d_in[0];
    const int*  ei = (const int*)d_in[1];
    const void* W1 = d_in[2];
    const void* b1 = d_in[3];
    const void* a1 = d_in[4];
    const void* W2 = d_in[5];
    const void* b2 = d_in[6];

    size_t off = 0;
    auto alloc = [&](size_t bytes) { size_t p = off; off = (off + bytes + 255) & ~(size_t)255; return p; };
    char* ws = (char*)d_ws;
    int*            flags  = (int*)           (ws + alloc(1024));
    float*          dinv   = (float*)         (ws + alloc((size_t)NNODES * 4));
    int*            bcnt   = (int*)           (ws + alloc((size_t)NBUCK * 4));
    int*            bbase  = (int*)           (ws + alloc((size_t)(NBUCK + 1) * 4));
    int*            bcur   = (int*)           (ws + alloc((size_t)NBUCK * 4));
    int*            rowptr = (int*)           (ws + alloc(((size_t)NNODES + 1) * 4));
    unsigned*       ebuf   = (unsigned*)      (ws + alloc((size_t)NEDGES * 4));
    unsigned short* col    = (unsigned short*)(ws + alloc((size_t)NEDGES * 2));
    __hip_bfloat16* gA     = (__hip_bfloat16*)(ws + alloc((size_t)NNODES * HC * 2));
    __hip_bfloat16* gB     = (__hip_bfloat16*)(ws + alloc((size_t)NNODES * HC * 2));
    __hip_bfloat16* hA     = (__hip_bfloat16*)(ws + alloc((size_t)NNODES * HC * 2));
    __hip_bfloat16* hB     = (__hip_bfloat16*)(ws + alloc((size_t)NNODES * HC * 2));
    if (ws_size < off) return;   // ~33 MiB

    k_sniff<<<1, 64, 0, stream>>>((const unsigned*)x, (const unsigned*)ei, flags, bcnt);

    // ---- CSR build: XCD-local 2-pass counting sort by dst ----
    k_bcount<<<256, 256, 0, stream>>>(ei, bcnt, flags);
    k_bscan <<<1, 256, 0, stream>>>(bcnt, bbase, bcur, rowptr);
    k_part  <<<(NEDGES + PCHUNK - 1) / PCHUNK, 256, 0, stream>>>(ei, bcur, ebuf, flags);
    k_csr   <<<NBUCK, 256, 0, stream>>>(ebuf, bbase, rowptr, col, dinv);

    const int gemm_grid = (NNODES + TM - 1) / TM;       // 782
    const int aggr_grid = (NNODES + 3) / 4;             // 12500 (4 rows/block)

    // ---- layer 1: GEMM -> split g; two half-passes -> split h (PReLU) ----
    k_gemm_mfma<<<gemm_grid, 256, 0, stream>>>(x, nullptr, nullptr, W1, dinv, gA, gB, flags);
    k_aggr<<<aggr_grid, 256, 0, stream>>>(gA, rowptr, col, dinv, b1, a1, hA, flags, 1, 0,  HC, 0);
    k_aggr<<<aggr_grid, 256, 0, stream>>>(gB, rowptr, col, dinv, b1, a1, hB, flags, 1, HC, HC, 0);

    // ---- layer 2: GEMM from split h -> split g; two half-passes -> d_out ----
    k_gemm_mfma<<<gemm_grid, 256, 0, stream>>>(nullptr, hA, hB, W2, dinv, gA, gB, flags);
    k_aggr<<<aggr_grid, 256, 0, stream>>>(gA, rowptr, col, dinv, b2, a1, d_out, flags, 0, 0,  DIM, 0);
    k_aggr<<<aggr_grid, 256, 0, stream>>>(gB, rowptr, col, dinv, b2, a1, d_out, flags, 0, HC, DIM, HC);
}

// Round 13
// 239.576 us; speedup vs baseline: 1.2033x; 1.2033x over previous
//
#include <hip/hip_runtime.h>
#include <hip/hip_bf16.h>

// N=50000 nodes, E=800000 edges, D=96 (in = hidden = out)
#define NNODES 50000
#define NEDGES 800000
#define DIM    96
#define NBUCK  196      // ceil(N/256): bucket = dst >> 8
#define PCHUNK 3125     // edges per partition block (256 * 3125 = 800000)
#define TM     64       // rows per GEMM block
#define XPAD   104      // LDS row stride (bf16), 16B-aligned

typedef __attribute__((ext_vector_type(8))) short   short8;   // 8 bf16 = 4 VGPRs
typedef __attribute__((ext_vector_type(4))) float   float4v;  // MFMA acc

// flags[0] = 1 if float tensors are bf16, 0 if f32
// flags[1] = 1 if edge_index is int64, 0 if int32
__device__ __forceinline__ float loadF(const void* p, long i, int isbf) {
    return isbf ? __bfloat162float(((const __hip_bfloat16*)p)[i])
                : ((const float*)p)[i];
}
__device__ __forceinline__ int clampN(int v) {
    return v < 0 ? 0 : (v >= NNODES ? NNODES - 1 : v);
}
__device__ __forceinline__ int edgeDst(const int* w, int e, int is64) {
    return clampN(is64 ? w[2 * (NEDGES + e)] : w[NEDGES + e]);
}
__device__ __forceinline__ int edgeSrc(const int* w, int e, int is64) {
    return clampN(is64 ? w[2 * e] : w[e]);
}

// single wave: sniff dtypes; also zero bcnt (replaces a memset dispatch)
__global__ void k_sniff(const unsigned* __restrict__ xw,
                        const unsigned* __restrict__ ew,
                        int* __restrict__ flags,
                        int* __restrict__ bcnt) {
    int lane = threadIdx.x;
    for (int i = lane; i < NBUCK; i += 64) bcnt[i] = 0;
    int bad = 0, nz = 0;
    for (int r = 0; r < 4; ++r) {
        unsigned w  = xw[lane + 64 * r];
        unsigned lo = w & 0xffffu;
        unsigned ex = (lo >> 7) & 0xffu;
        if (!(lo == 0u || (ex >= 90u && ex <= 145u))) bad++;
        unsigned o = ew[2 * (lane + 64 * r) + 1];
        if (o != 0u) nz++;
    }
    for (int off = 32; off; off >>= 1) {
        bad += __shfl_down(bad, off);
        nz  += __shfl_down(nz,  off);
    }
    if (lane == 0) {
        flags[0] = (bad <= 32) ? 1 : 0;
        flags[1] = (nz  <  4) ? 1 : 0;
    }
}

// bucket counts: per-block LDS histogram, then 196 global adds per block
__global__ __launch_bounds__(256) void k_bcount(const int* __restrict__ w,
                                                int* __restrict__ bcnt,
                                                const int* __restrict__ flags) {
    __shared__ int h[NBUCK];
    const int is64 = flags[1];
    for (int i = threadIdx.x; i < NBUCK; i += 256) h[i] = 0;
    __syncthreads();
    const int nth = gridDim.x * blockDim.x;
    for (int e = blockIdx.x * blockDim.x + threadIdx.x; e < NEDGES; e += nth)
        atomicAdd(&h[edgeDst(w, e, is64) >> 8], 1);
    __syncthreads();
    for (int i = threadIdx.x; i < NBUCK; i += 256)
        if (h[i]) atomicAdd(&bcnt[i], h[i]);
}

// exclusive scan of 196 bucket counts -> bbase, bcur; seal rowptr[N]
__global__ __launch_bounds__(256) void k_bscan(const int* __restrict__ bcnt,
                                               int* __restrict__ bbase,
                                               int* __restrict__ bcur,
                                               int* __restrict__ rowptr) {
    __shared__ int s[256];
    const int tid = threadIdx.x;
    int v = (tid < NBUCK) ? bcnt[tid] : 0;
    s[tid] = v;
    __syncthreads();
    for (int off = 1; off < 256; off <<= 1) {
        int t = (tid >= off) ? s[tid - off] : 0;
        __syncthreads();
        s[tid] += t;
        __syncthreads();
    }
    int excl = s[tid] - v;
    if (tid < NBUCK) { bbase[tid] = excl; bcur[tid] = excl; }
    if (tid == 0) { bbase[NBUCK] = NEDGES; rowptr[NNODES] = NEDGES; }
}

// partition edges into bucket regions as packed (dst<<16)|src u32 records.
// Per-(block,bucket) ranges are contiguous (~64B bursts) -> writes merge in L2.
__global__ __launch_bounds__(256) void k_part(const int* __restrict__ w,
                                              int* __restrict__ bcur,
                                              unsigned* __restrict__ ebuf,
                                              const int* __restrict__ flags) {
    __shared__ int h[NBUCK];
    __shared__ int base[NBUCK];
    const int is64 = flags[1];
    const int e0 = blockIdx.x * PCHUNK;
    const int e1 = (e0 + PCHUNK < NEDGES) ? e0 + PCHUNK : NEDGES;

    for (int i = threadIdx.x; i < NBUCK; i += 256) h[i] = 0;
    __syncthreads();
    for (int e = e0 + threadIdx.x; e < e1; e += 256)
        atomicAdd(&h[edgeDst(w, e, is64) >> 8], 1);
    __syncthreads();
    for (int i = threadIdx.x; i < NBUCK; i += 256) {
        int c = h[i];
        base[i] = c ? atomicAdd(&bcur[i], c) : 0;
        h[i] = 0;                        // reuse as local cursor
    }
    __syncthreads();
    for (int e = e0 + threadIdx.x; e < e1; e += 256) {
        int s = edgeSrc(w, e, is64);
        int d = edgeDst(w, e, is64);
        int b = d >> 8;
        int pos = base[b] + atomicAdd(&h[b], 1);
        ebuf[pos] = ((unsigned)d << 16) | (unsigned)s;
    }
}

// per-bucket local CSR: histogram 256 local dsts, scan -> rowptr/dinv,
// LDS-cursor scatter of col (uint16). All writes block/XCD-local.
__global__ __launch_bounds__(256) void k_csr(const unsigned* __restrict__ ebuf,
                                             const int* __restrict__ bbase,
                                             int* __restrict__ rowptr,
                                             unsigned short* __restrict__ col,
                                             float* __restrict__ dinv) {
    __shared__ int h[256];
    __shared__ int sc[256];
    __shared__ int cur[256];
    const int b   = blockIdx.x;
    const int tid = threadIdx.x;
    const int e0 = bbase[b], e1 = bbase[b + 1];

    h[tid] = 0;
    __syncthreads();
    for (int e = e0 + tid; e < e1; e += 256)
        atomicAdd(&h[(ebuf[e] >> 16) & 255], 1);
    __syncthreads();
    int v = h[tid];
    sc[tid] = v;
    __syncthreads();
    for (int off = 1; off < 256; off <<= 1) {
        int t = (tid >= off) ? sc[tid - off] : 0;
        __syncthreads();
        sc[tid] += t;
        __syncthreads();
    }
    int start = e0 + sc[tid] - v;       // exclusive
    cur[tid] = start;
    int node = b * 256 + tid;
    if (node < NNODES) {
        rowptr[node] = start;
        dinv[node] = rsqrtf((float)v + 1.0f);   // +1 self loop
    }
    __syncthreads();
    for (int e = e0 + tid; e < e1; e += 256) {
        unsigned r = ebuf[e];
        int dl = (r >> 16) & 255;
        int pos = atomicAdd(&cur[dl], 1);
        col[pos] = (unsigned short)(r & 0xffffu);
    }
}

// MFMA GEMM: g[row,:] = bf16( dinv[row] * (X[row,:] @ W) )
// block = 256 (4 waves), 64 rows/block; X strip + W^T staged in LDS as bf16.
__global__ __launch_bounds__(256) void k_gemm_mfma(
        const void* __restrict__ X, int x_force_bf16,
        const void* __restrict__ W,
        const float* __restrict__ dinv,
        __hip_bfloat16* __restrict__ g,
        const int* __restrict__ flags) {
    __shared__ __hip_bfloat16 Xs[TM * XPAD];
    __shared__ __hip_bfloat16 Wt[DIM * XPAD];

    const int t    = threadIdx.x;
    const int fbf  = flags[0];
    const int xbf  = x_force_bf16 ? 1 : fbf;
    const int row0 = blockIdx.x * TM;

    for (int idx = t; idx < DIM * DIM; idx += 256) {
        int k = idx / DIM, n = idx - k * DIM;
        Wt[n * XPAD + k] = __float2bfloat16(loadF(W, idx, fbf));
    }
    for (int idx = t; idx < TM * DIM; idx += 256) {
        int r = idx / DIM, c = idx - r * DIM;
        int gr = row0 + r;
        float v = (gr < NNODES) ? loadF(X, (long)gr * DIM + c, xbf) : 0.f;
        Xs[r * XPAD + c] = __float2bfloat16(v);
    }
    __syncthreads();

    const int wave = t >> 6;
    const int lane = t & 63;
    const int m    = lane & 15;
    const int quad = lane >> 4;

    const short* xsp = (const short*)Xs;
    short8 a[3];
#pragma unroll
    for (int kt = 0; kt < 3; ++kt)
        a[kt] = *(const short8*)(xsp + (wave * 16 + m) * XPAD + kt * 32 + quad * 8);

    float dv[4];
#pragma unroll
    for (int r2 = 0; r2 < 4; ++r2) {
        int gr = row0 + wave * 16 + quad * 4 + r2;
        dv[r2] = (gr < NNODES) ? dinv[gr] : 0.f;
    }

    const short* wtp = (const short*)Wt;
#pragma unroll
    for (int nt = 0; nt < 6; ++nt) {
        float4v acc = {0.f, 0.f, 0.f, 0.f};
#pragma unroll
        for (int kt = 0; kt < 3; ++kt) {
            short8 b = *(const short8*)(wtp + (nt * 16 + m) * XPAD + kt * 32 + quad * 8);
            acc = __builtin_amdgcn_mfma_f32_16x16x32_bf16(a[kt], b, acc, 0, 0, 0);
        }
#pragma unroll
        for (int r2 = 0; r2 < 4; ++r2) {
            int gr = row0 + wave * 16 + quad * 4 + r2;
            if (gr < NNODES)
                g[(size_t)gr * DIM + nt * 16 + m] = __float2bfloat16(acc[r2] * dv[r2]);
        }
    }
}

// aggregate + epilogue: ONE WAVE per destination row, lanes 0..47 hold
// bfloat162 column pairs (one gather instruction = one 192B row, 3 lines).
// 16-deep unroll for MLP (latency-bound vs LLC); col[] reads wave-uniform.
__global__ __launch_bounds__(256) void k_aggr(
        const __hip_bfloat16* __restrict__ g,
        const int* __restrict__ rowptr,
        const unsigned short* __restrict__ col,
        const float* __restrict__ dinv,
        const void* __restrict__ b,
        const void* __restrict__ a1,
        void* __restrict__ out,
        const int* __restrict__ flags, int prelu) {
    const int wave = threadIdx.x >> 6;
    const int lane = threadIdx.x & 63;
    const int row  = blockIdx.x * 4 + wave;
    if (row >= NNODES) return;                       // wave-uniform
    const int fbf = flags[0];
    const __hip_bfloat162* gv = (const __hip_bfloat162*)g;
    const int c = lane;                              // 0..47 active

    float2 acc = {0.f, 0.f};
    if (c < 48) acc = __bfloat1622float2(gv[(size_t)row * 48 + c]);  // self loop

    const int p0 = rowptr[row], p1 = rowptr[row + 1];
    int i = p0;
    for (; i + 16 <= p1; i += 16) {                  // 16 gathers in flight
        int s[16];
#pragma unroll
        for (int k = 0; k < 16; ++k) s[k] = col[i + k];
        if (c < 48) {
            float2 v[16];
#pragma unroll
            for (int k = 0; k < 16; ++k)
                v[k] = __bfloat1622float2(gv[(size_t)s[k] * 48 + c]);
            float2 t0, t1, t2, t3;
            t0.x = (v[0].x + v[1].x) + (v[2].x + v[3].x);
            t0.y = (v[0].y + v[1].y) + (v[2].y + v[3].y);
            t1.x = (v[4].x + v[5].x) + (v[6].x + v[7].x);
            t1.y = (v[4].y + v[5].y) + (v[6].y + v[7].y);
            t2.x = (v[8].x + v[9].x) + (v[10].x + v[11].x);
            t2.y = (v[8].y + v[9].y) + (v[10].y + v[11].y);
            t3.x = (v[12].x + v[13].x) + (v[14].x + v[15].x);
            t3.y = (v[12].y + v[13].y) + (v[14].y + v[15].y);
            acc.x += (t0.x + t1.x) + (t2.x + t3.x);
            acc.y += (t0.y + t1.y) + (t2.y + t3.y);
        }
    }
    for (; i + 8 <= p1; i += 8) {
        int s[8];
#pragma unroll
        for (int k = 0; k < 8; ++k) s[k] = col[i + k];
        if (c < 48) {
            float2 v[8];
#pragma unroll
            for (int k = 0; k < 8; ++k)
                v[k] = __bfloat1622float2(gv[(size_t)s[k] * 48 + c]);
            acc.x += ((v[0].x + v[1].x) + (v[2].x + v[3].x))
                   + ((v[4].x + v[5].x) + (v[6].x + v[7].x));
            acc.y += ((v[0].y + v[1].y) + (v[2].y + v[3].y))
                   + ((v[4].y + v[5].y) + (v[6].y + v[7].y));
        }
    }
    for (; i + 4 <= p1; i += 4) {
        int s0 = col[i], s1 = col[i+1], s2 = col[i+2], s3 = col[i+3];
        if (c < 48) {
            float2 v0 = __bfloat1622float2(gv[(size_t)s0 * 48 + c]);
            float2 v1 = __bfloat1622float2(gv[(size_t)s1 * 48 + c]);
            float2 v2 = __bfloat1622float2(gv[(size_t)s2 * 48 + c]);
            float2 v3 = __bfloat1622float2(gv[(size_t)s3 * 48 + c]);
            acc.x += (v0.x + v1.x) + (v2.x + v3.x);
            acc.y += (v0.y + v1.y) + (v2.y + v3.y);
        }
    }
    for (; i < p1; ++i) {
        int s = col[i];
        if (c < 48) {
            float2 v = __bfloat1622float2(gv[(size_t)s * 48 + c]);
            acc.x += v.x; acc.y += v.y;
        }
    }

    if (c < 48) {
        float dv = dinv[row];
        float vx = dv * acc.x + loadF(b, 2 * c,     fbf);
        float vy = dv * acc.y + loadF(b, 2 * c + 1, fbf);
        if (prelu) {
            float alpha = loadF(a1, 0, fbf);
            vx = vx > 0.f ? vx : alpha * vx;
            vy = vy > 0.f ? vy : alpha * vy;
            ((__hip_bfloat162*)out)[(size_t)row * 48 + c] =
                __halves2bfloat162(__float2bfloat16(vx), __float2bfloat16(vy));
        } else if (fbf) {
            ((__hip_bfloat162*)out)[(size_t)row * 48 + c] =
                __halves2bfloat162(__float2bfloat16(vx), __float2bfloat16(vy));
        } else {
            float2 o; o.x = vx; o.y = vy;
            ((float2*)out)[(size_t)row * 48 + c] = o;
        }
    }
}

extern "C" void kernel_launch(void* const* d_in, const int* in_sizes, int n_in,
                              void* d_out, int out_size, void* d_ws, size_t ws_size,
                              hipStream_t stream) {
    const void* x  = d_in[0];
    const int*  ei = (const int*)d_in[1];
    const void* W1 = d_in[2];
    const void* b1 = d_in[3];
    const void* a1 = d_in[4];
    const void* W2 = d_in[5];
    const void* b2 = d_in[6];

    size_t off = 0;
    auto alloc = [&](size_t bytes) { size_t p = off; off = (off + bytes + 255) & ~(size_t)255; return p; };
    char* ws = (char*)d_ws;
    int*            flags  = (int*)           (ws + alloc(1024));
    float*          dinv   = (float*)         (ws + alloc((size_t)NNODES * 4));
    int*            bcnt   = (int*)           (ws + alloc((size_t)NBUCK * 4));
    int*            bbase  = (int*)           (ws + alloc((size_t)(NBUCK + 1) * 4));
    int*            bcur   = (int*)           (ws + alloc((size_t)NBUCK * 4));
    int*            rowptr = (int*)           (ws + alloc(((size_t)NNODES + 1) * 4));
    unsigned*       ebuf   = (unsigned*)      (ws + alloc((size_t)NEDGES * 4));
    unsigned short* col    = (unsigned short*)(ws + alloc((size_t)NEDGES * 2));
    __hip_bfloat16* g      = (__hip_bfloat16*)(ws + alloc((size_t)NNODES * DIM * 2));
    __hip_bfloat16* g2     = (__hip_bfloat16*)(ws + alloc((size_t)NNODES * DIM * 2));
    if (ws_size < off) return;   // ~23.5 MiB

    k_sniff<<<1, 64, 0, stream>>>((const unsigned*)x, (const unsigned*)ei, flags, bcnt);

    // ---- CSR build: XCD-local 2-pass counting sort by dst ----
    k_bcount<<<256, 256, 0, stream>>>(ei, bcnt, flags);
    k_bscan <<<1, 256, 0, stream>>>(bcnt, bbase, bcur, rowptr);
    k_part  <<<(NEDGES + PCHUNK - 1) / PCHUNK, 256, 0, stream>>>(ei, bcur, ebuf, flags);
    k_csr   <<<NBUCK, 256, 0, stream>>>(ebuf, bbase, rowptr, col, dinv);

    const int gemm_grid = (NNODES + TM - 1) / TM;       // 782
    const int aggr_grid = (NNODES + 3) / 4;             // 12500 (4 rows/block)

    // ---- layer 1 ----
    k_gemm_mfma<<<gemm_grid, 256, 0, stream>>>(x, 0, W1, dinv, g, flags);
    k_aggr<<<aggr_grid, 256, 0, stream>>>(g, rowptr, col, dinv, b1, a1, g2, flags, 1);

    // ---- layer 2 ----
    k_gemm_mfma<<<gemm_grid, 256, 0, stream>>>(g2, 1, W2, dinv, g, flags);
    k_aggr<<<aggr_grid, 256, 0, stream>>>(g, rowptr, col, dinv, b2, a1, d_out, flags, 0);
}

// Round 14
// 236.964 us; speedup vs baseline: 1.2166x; 1.0110x over previous
//
#include <hip/hip_runtime.h>
#include <hip/hip_bf16.h>

// N=50000 nodes, E=800000 edges, D=96 (in = hidden = out)
#define NNODES 50000
#define NEDGES 800000
#define DIM    96
#define NBUCK  196      // ceil(N/256): bucket = dst >> 8
#define PCHUNK 3125     // edges per partition block (256 * 3125 = 800000)
#define TM     64       // rows per GEMM block
#define XPAD   104      // LDS row stride (bf16), 16B-aligned

typedef __attribute__((ext_vector_type(8))) short   short8;   // 8 bf16 = 4 VGPRs
typedef __attribute__((ext_vector_type(4))) float   float4v;  // MFMA acc

// flags[0] = 1 if float tensors are bf16, 0 if f32
// flags[1] = 1 if edge_index is int64, 0 if int32
__device__ __forceinline__ float loadF(const void* p, long i, int isbf) {
    return isbf ? __bfloat162float(((const __hip_bfloat16*)p)[i])
                : ((const float*)p)[i];
}
__device__ __forceinline__ int clampN(int v) {
    return v < 0 ? 0 : (v >= NNODES ? NNODES - 1 : v);
}
__device__ __forceinline__ int edgeDst(const int* w, int e, int is64) {
    return clampN(is64 ? w[2 * (NEDGES + e)] : w[NEDGES + e]);
}
__device__ __forceinline__ int edgeSrc(const int* w, int e, int is64) {
    return clampN(is64 ? w[2 * e] : w[e]);
}

// single wave: sniff dtypes; also zero bcnt + bcur (replaces memset dispatches)
__global__ void k_sniff(const unsigned* __restrict__ xw,
                        const unsigned* __restrict__ ew,
                        int* __restrict__ flags,
                        int* __restrict__ bcnt,
                        int* __restrict__ bcur) {
    int lane = threadIdx.x;
    for (int i = lane; i < NBUCK; i += 64) { bcnt[i] = 0; bcur[i] = 0; }
    int bad = 0, nz = 0;
    for (int r = 0; r < 4; ++r) {
        unsigned w  = xw[lane + 64 * r];
        unsigned lo = w & 0xffffu;
        unsigned ex = (lo >> 7) & 0xffu;
        if (!(lo == 0u || (ex >= 90u && ex <= 145u))) bad++;
        unsigned o = ew[2 * (lane + 64 * r) + 1];
        if (o != 0u) nz++;
    }
    for (int off = 32; off; off >>= 1) {
        bad += __shfl_down(bad, off);
        nz  += __shfl_down(nz,  off);
    }
    if (lane == 0) {
        flags[0] = (bad <= 32) ? 1 : 0;
        flags[1] = (nz  <  4) ? 1 : 0;
    }
}

// bucket counts: per-block LDS histogram, then 196 global adds per block
__global__ __launch_bounds__(256) void k_bcount(const int* __restrict__ w,
                                                int* __restrict__ bcnt,
                                                const int* __restrict__ flags) {
    __shared__ int h[NBUCK];
    const int is64 = flags[1];
    for (int i = threadIdx.x; i < NBUCK; i += 256) h[i] = 0;
    __syncthreads();
    const int nth = gridDim.x * blockDim.x;
    for (int e = blockIdx.x * blockDim.x + threadIdx.x; e < NEDGES; e += nth)
        atomicAdd(&h[edgeDst(w, e, is64) >> 8], 1);
    __syncthreads();
    for (int i = threadIdx.x; i < NBUCK; i += 256)
        if (h[i]) atomicAdd(&bcnt[i], h[i]);
}

// partition edges into bucket regions as packed (dst<<16)|src u32 records.
// Bucket bases come from a per-block self-scan of bcnt (no k_bscan dispatch);
// bcur is a zero-based global cursor per bucket.
__global__ __launch_bounds__(256) void k_part(const int* __restrict__ w,
                                              const int* __restrict__ bcnt,
                                              int* __restrict__ bcur,
                                              unsigned* __restrict__ ebuf,
                                              const int* __restrict__ flags) {
    __shared__ int sbase[256];       // inclusive scan of bcnt
    __shared__ int h[NBUCK];
    __shared__ int base[NBUCK];
    const int is64 = flags[1];
    const int tid  = threadIdx.x;
    const int e0 = blockIdx.x * PCHUNK;
    const int e1 = (e0 + PCHUNK < NEDGES) ? e0 + PCHUNK : NEDGES;

    // self-scan: sbase[i] = sum_{j<=i} bcnt[j]
    int v = (tid < NBUCK) ? bcnt[tid] : 0;
    sbase[tid] = v;
    __syncthreads();
    for (int off = 1; off < 256; off <<= 1) {
        int t = (tid >= off) ? sbase[tid - off] : 0;
        __syncthreads();
        sbase[tid] += t;
        __syncthreads();
    }
    int excl = sbase[tid] - v;       // exclusive base for bucket tid
    __syncthreads();
    sbase[tid] = excl;
    if (tid < NBUCK) h[tid] = 0;
    __syncthreads();

    for (int e = e0 + tid; e < e1; e += 256)
        atomicAdd(&h[edgeDst(w, e, is64) >> 8], 1);
    __syncthreads();
    for (int i = tid; i < NBUCK; i += 256) {
        int c = h[i];
        base[i] = c ? sbase[i] + atomicAdd(&bcur[i], c) : 0;
        h[i] = 0;                    // reuse as local cursor
    }
    __syncthreads();
    for (int e = e0 + tid; e < e1; e += 256) {
        int s = edgeSrc(w, e, is64);
        int d = edgeDst(w, e, is64);
        int b = d >> 8;
        int pos = base[b] + atomicAdd(&h[b], 1);
        ebuf[pos] = ((unsigned)d << 16) | (unsigned)s;
    }
}

// per-bucket local CSR (512 threads): self-scan bucket bases, histogram 256
// local dsts, scan -> rowptr/dinv, LDS-cursor scatter of col (uint16).
__global__ __launch_bounds__(512) void k_csr(const unsigned* __restrict__ ebuf,
                                             const int* __restrict__ bcnt,
                                             int* __restrict__ rowptr,
                                             unsigned short* __restrict__ col,
                                             float* __restrict__ dinv) {
    __shared__ int gbase[256];       // inclusive scan of bcnt
    __shared__ int h[256];
    __shared__ int sc[256];
    __shared__ int cur[256];
    const int b   = blockIdx.x;
    const int tid = threadIdx.x;

    // self-scan of the 196 bucket counts (first 256 threads)
    if (tid < 256) gbase[tid] = (tid < NBUCK) ? bcnt[tid] : 0;
    __syncthreads();
    for (int off = 1; off < 256; off <<= 1) {
        int t = 0;
        if (tid < 256 && tid >= off) t = gbase[tid - off];
        __syncthreads();
        if (tid < 256) gbase[tid] += t;
        __syncthreads();
    }
    const int e0 = (b == 0) ? 0 : gbase[b - 1];
    const int e1 = gbase[b];
    __syncthreads();

    if (tid < 256) h[tid] = 0;
    __syncthreads();
    for (int e = e0 + tid; e < e1; e += 512)
        atomicAdd(&h[(ebuf[e] >> 16) & 255], 1);
    __syncthreads();
    int v = 0;
    if (tid < 256) { v = h[tid]; sc[tid] = v; }
    __syncthreads();
    for (int off = 1; off < 256; off <<= 1) {
        int t = 0;
        if (tid < 256 && tid >= off) t = sc[tid - off];
        __syncthreads();
        if (tid < 256) sc[tid] += t;
        __syncthreads();
    }
    if (tid < 256) {
        int start = e0 + sc[tid] - v;    // exclusive
        cur[tid] = start;
        int node = b * 256 + tid;
        if (node < NNODES) {
            rowptr[node] = start;
            dinv[node] = rsqrtf((float)v + 1.0f);   // +1 self loop
        }
    }
    if (b == 0 && tid == 0) rowptr[NNODES] = NEDGES;
    __syncthreads();
    for (int e = e0 + tid; e < e1; e += 512) {
        unsigned r = ebuf[e];
        int dl = (r >> 16) & 255;
        int pos = atomicAdd(&cur[dl], 1);
        col[pos] = (unsigned short)(r & 0xffffu);
    }
}

// MFMA GEMM: g[row,:] = bf16( dinv[row] * (X[row,:] @ W) )
// block = 256 (4 waves), 64 rows/block; X strip + W^T staged in LDS as bf16.
__global__ __launch_bounds__(256) void k_gemm_mfma(
        const void* __restrict__ X, int x_force_bf16,
        const void* __restrict__ W,
        const float* __restrict__ dinv,
        __hip_bfloat16* __restrict__ g,
        const int* __restrict__ flags) {
    __shared__ __hip_bfloat16 Xs[TM * XPAD];
    __shared__ __hip_bfloat16 Wt[DIM * XPAD];

    const int t    = threadIdx.x;
    const int fbf  = flags[0];
    const int xbf  = x_force_bf16 ? 1 : fbf;
    const int row0 = blockIdx.x * TM;

    for (int idx = t; idx < DIM * DIM; idx += 256) {
        int k = idx / DIM, n = idx - k * DIM;
        Wt[n * XPAD + k] = __float2bfloat16(loadF(W, idx, fbf));
    }
    for (int idx = t; idx < TM * DIM; idx += 256) {
        int r = idx / DIM, c = idx - r * DIM;
        int gr = row0 + r;
        float v = (gr < NNODES) ? loadF(X, (long)gr * DIM + c, xbf) : 0.f;
        Xs[r * XPAD + c] = __float2bfloat16(v);
    }
    __syncthreads();

    const int wave = t >> 6;
    const int lane = t & 63;
    const int m    = lane & 15;
    const int quad = lane >> 4;

    const short* xsp = (const short*)Xs;
    short8 a[3];
#pragma unroll
    for (int kt = 0; kt < 3; ++kt)
        a[kt] = *(const short8*)(xsp + (wave * 16 + m) * XPAD + kt * 32 + quad * 8);

    float dv[4];
#pragma unroll
    for (int r2 = 0; r2 < 4; ++r2) {
        int gr = row0 + wave * 16 + quad * 4 + r2;
        dv[r2] = (gr < NNODES) ? dinv[gr] : 0.f;
    }

    const short* wtp = (const short*)Wt;
#pragma unroll
    for (int nt = 0; nt < 6; ++nt) {
        float4v acc = {0.f, 0.f, 0.f, 0.f};
#pragma unroll
        for (int kt = 0; kt < 3; ++kt) {
            short8 b = *(const short8*)(wtp + (nt * 16 + m) * XPAD + kt * 32 + quad * 8);
            acc = __builtin_amdgcn_mfma_f32_16x16x32_bf16(a[kt], b, acc, 0, 0, 0);
        }
#pragma unroll
        for (int r2 = 0; r2 < 4; ++r2) {
            int gr = row0 + wave * 16 + quad * 4 + r2;
            if (gr < NNODES)
                g[(size_t)gr * DIM + nt * 16 + m] = __float2bfloat16(acc[r2] * dv[r2]);
        }
    }
}

// aggregate + epilogue: ONE WAVE per destination row, lanes 0..47 hold
// bfloat162 column pairs (one gather instruction = one 192B row).
// 16-deep unroll for MLP (latency-bound vs LLC); col[] reads wave-uniform.
__global__ __launch_bounds__(256) void k_aggr(
        const __hip_bfloat16* __restrict__ g,
        const int* __restrict__ rowptr,
        const unsigned short* __restrict__ col,
        const float* __restrict__ dinv,
        const void* __restrict__ b,
        const void* __restrict__ a1,
        void* __restrict__ out,
        const int* __restrict__ flags, int prelu) {
    const int wave = threadIdx.x >> 6;
    const int lane = threadIdx.x & 63;
    const int row  = blockIdx.x * 4 + wave;
    if (row >= NNODES) return;                       // wave-uniform
    const int fbf = flags[0];
    const __hip_bfloat162* gv = (const __hip_bfloat162*)g;
    const int c = lane;                              // 0..47 active

    float2 acc = {0.f, 0.f};
    if (c < 48) acc = __bfloat1622float2(gv[(size_t)row * 48 + c]);  // self loop

    const int p0 = rowptr[row], p1 = rowptr[row + 1];
    int i = p0;
    for (; i + 16 <= p1; i += 16) {                  // 16 gathers in flight
        int s[16];
#pragma unroll
        for (int k = 0; k < 16; ++k) s[k] = col[i + k];
        if (c < 48) {
            float2 v[16];
#pragma unroll
            for (int k = 0; k < 16; ++k)
                v[k] = __bfloat1622float2(gv[(size_t)s[k] * 48 + c]);
            float2 t0, t1, t2, t3;
            t0.x = (v[0].x + v[1].x) + (v[2].x + v[3].x);
            t0.y = (v[0].y + v[1].y) + (v[2].y + v[3].y);
            t1.x = (v[4].x + v[5].x) + (v[6].x + v[7].x);
            t1.y = (v[4].y + v[5].y) + (v[6].y + v[7].y);
            t2.x = (v[8].x + v[9].x) + (v[10].x + v[11].x);
            t2.y = (v[8].y + v[9].y) + (v[10].y + v[11].y);
            t3.x = (v[12].x + v[13].x) + (v[14].x + v[15].x);
            t3.y = (v[12].y + v[13].y) + (v[14].y + v[15].y);
            acc.x += (t0.x + t1.x) + (t2.x + t3.x);
            acc.y += (t0.y + t1.y) + (t2.y + t3.y);
        }
    }
    for (; i + 8 <= p1; i += 8) {
        int s[8];
#pragma unroll
        for (int k = 0; k < 8; ++k) s[k] = col[i + k];
        if (c < 48) {
            float2 v[8];
#pragma unroll
            for (int k = 0; k < 8; ++k)
                v[k] = __bfloat1622float2(gv[(size_t)s[k] * 48 + c]);
            acc.x += ((v[0].x + v[1].x) + (v[2].x + v[3].x))
                   + ((v[4].x + v[5].x) + (v[6].x + v[7].x));
            acc.y += ((v[0].y + v[1].y) + (v[2].y + v[3].y))
                   + ((v[4].y + v[5].y) + (v[6].y + v[7].y));
        }
    }
    for (; i + 4 <= p1; i += 4) {
        int s0 = col[i], s1 = col[i+1], s2 = col[i+2], s3 = col[i+3];
        if (c < 48) {
            float2 v0 = __bfloat1622float2(gv[(size_t)s0 * 48 + c]);
            float2 v1 = __bfloat1622float2(gv[(size_t)s1 * 48 + c]);
            float2 v2 = __bfloat1622float2(gv[(size_t)s2 * 48 + c]);
            float2 v3 = __bfloat1622float2(gv[(size_t)s3 * 48 + c]);
            acc.x += (v0.x + v1.x) + (v2.x + v3.x);
            acc.y += (v0.y + v1.y) + (v2.y + v3.y);
        }
    }
    for (; i < p1; ++i) {
        int s = col[i];
        if (c < 48) {
            float2 v = __bfloat1622float2(gv[(size_t)s * 48 + c]);
            acc.x += v.x; acc.y += v.y;
        }
    }

    if (c < 48) {
        float dv = dinv[row];
        float vx = dv * acc.x + loadF(b, 2 * c,     fbf);
        float vy = dv * acc.y + loadF(b, 2 * c + 1, fbf);
        if (prelu) {
            float alpha = loadF(a1, 0, fbf);
            vx = vx > 0.f ? vx : alpha * vx;
            vy = vy > 0.f ? vy : alpha * vy;
            ((__hip_bfloat162*)out)[(size_t)row * 48 + c] =
                __halves2bfloat162(__float2bfloat16(vx), __float2bfloat16(vy));
        } else if (fbf) {
            ((__hip_bfloat162*)out)[(size_t)row * 48 + c] =
                __halves2bfloat162(__float2bfloat16(vx), __float2bfloat16(vy));
        } else {
            float2 o; o.x = vx; o.y = vy;
            ((float2*)out)[(size_t)row * 48 + c] = o;
        }
    }
}

extern "C" void kernel_launch(void* const* d_in, const int* in_sizes, int n_in,
                              void* d_out, int out_size, void* d_ws, size_t ws_size,
                              hipStream_t stream) {
    const void* x  = d_in[0];
    const int*  ei = (const int*)d_in[1];
    const void* W1 = d_in[2];
    const void* b1 = d_in[3];
    const void* a1 = d_in[4];
    const void* W2 = d_in[5];
    const void* b2 = d_in[6];

    size_t off = 0;
    auto alloc = [&](size_t bytes) { size_t p = off; off = (off + bytes + 255) & ~(size_t)255; return p; };
    char* ws = (char*)d_ws;
    int*            flags  = (int*)           (ws + alloc(1024));
    float*          dinv   = (float*)         (ws + alloc((size_t)NNODES * 4));
    int*            bcnt   = (int*)           (ws + alloc((size_t)NBUCK * 4));
    int*            bcur   = (int*)           (ws + alloc((size_t)NBUCK * 4));
    int*            rowptr = (int*)           (ws + alloc(((size_t)NNODES + 1) * 4));
    unsigned*       ebuf   = (unsigned*)      (ws + alloc((size_t)NEDGES * 4));
    unsigned short* col    = (unsigned short*)(ws + alloc((size_t)NEDGES * 2));
    __hip_bfloat16* g      = (__hip_bfloat16*)(ws + alloc((size_t)NNODES * DIM * 2));
    __hip_bfloat16* g2     = (__hip_bfloat16*)(ws + alloc((size_t)NNODES * DIM * 2));
    if (ws_size < off) return;   // ~23.5 MiB

    k_sniff<<<1, 64, 0, stream>>>((const unsigned*)x, (const unsigned*)ei, flags, bcnt, bcur);

    // ---- CSR build: XCD-local 2-pass counting sort by dst (self-scanned) ----
    k_bcount<<<256, 256, 0, stream>>>(ei, bcnt, flags);
    k_part  <<<(NEDGES + PCHUNK - 1) / PCHUNK, 256, 0, stream>>>(ei, bcnt, bcur, ebuf, flags);
    k_csr   <<<NBUCK, 512, 0, stream>>>(ebuf, bcnt, rowptr, col, dinv);

    const int gemm_grid = (NNODES + TM - 1) / TM;       // 782
    const int aggr_grid = (NNODES + 3) / 4;             // 12500 (4 rows/block)

    // ---- layer 1 ----
    k_gemm_mfma<<<gemm_grid, 256, 0, stream>>>(x, 0, W1, dinv, g, flags);
    k_aggr<<<aggr_grid, 256, 0, stream>>>(g, rowptr, col, dinv, b1, a1, g2, flags, 1);

    // ---- layer 2 ----
    k_gemm_mfma<<<gemm_grid, 256, 0, stream>>>(g2, 1, W2, dinv, g, flags);
    k_aggr<<<aggr_grid, 256, 0, stream>>>(g, rowptr, col, dinv, b2, a1, d_out, flags, 0);
}